// Round 6
// baseline (297.159 us; speedup 1.0000x reference)
//
#include <hip/hip_runtime.h>
#include <stdint.h>
#include <math.h>

// Problem constants (fixed by the reference)
constexpr int CB = 2;      // batch
constexpr int CS = 2048;   // seq (cutoff)
constexpr int CD = 1024;   // dmodel
constexpr int CE = 16;     // experts
constexpr int CK = 256;    // topk

typedef short bf16x8 __attribute__((ext_vector_type(8)));
typedef float f32x4 __attribute__((ext_vector_type(4)));

typedef __attribute__((address_space(3))) unsigned short lds_us;

// ds_read_b128 hidden from the waitcnt legalizer; ordering vs MFMA is enforced
// by the "+v" register ties on the explicit lgkmcnt asm (rule: ties = data dep).
__device__ __forceinline__ bf16x8 ds_read128(const lds_us* p) {
    bf16x8 v;
    asm volatile("ds_read_b128 %0, %1" : "=v"(v) : "v"(p));
    return v;
}

__device__ inline unsigned short f2bf(float f) {
    union { float f; uint32_t u; } v; v.f = f;
    uint32_t u = v.u;
    uint32_t r = (u + 0x7FFFu + ((u >> 16) & 1u)) >> 16;
    return (unsigned short)r;
}

// ---------------- K1a: partial logits over a 64-d slice (+ zero y) ----------
__global__ __launch_bounds__(256)
void logits_part_kernel(const float* __restrict__ x,
                        const float* __restrict__ gate,
                        float* __restrict__ part,
                        float* __restrict__ y) {
    const int tt = blockIdx.x;       // token tile (256 tokens)
    const int dt = blockIdx.y;       // d tile (64 d)
    const int tid = threadIdx.x;

    // fold the y-zeroing in here (saves a hipMemsetAsync launch node).
    {
        const int bb = dt * 16 + tt;
        float* yb = y + (size_t)bb * 16384 + tid * 4;
        const f32x4 z = {0.f, 0.f, 0.f, 0.f};
#pragma unroll
        for (int i = 0; i < 16; i++) *(f32x4*)(yb + i * 1024) = z;
    }

    __shared__ float Xs[256 * 17];

    float acc[CE];
#pragma unroll
    for (int e = 0; e < CE; e++) acc[e] = 0.0f;

    const int tokl = tid >> 2;           // staging row within 64-token group
    const int c4 = (tid & 3) << 2;       // staging col (0,4,8,12)

    for (int dch = 0; dch < 4; dch++) {
        const int dbase = dt * 64 + dch * 16;
        __syncthreads();
#pragma unroll
        for (int q = 0; q < 4; q++) {
            const int tok = q * 64 + tokl;
            const f32x4 v = *(const f32x4*)(x + ((size_t)(tt * 256 + tok)) * CD + dbase + c4);
            Xs[tok * 17 + c4 + 0] = v[0];
            Xs[tok * 17 + c4 + 1] = v[1];
            Xs[tok * 17 + c4 + 2] = v[2];
            Xs[tok * 17 + c4 + 3] = v[3];
        }
        __syncthreads();
#pragma unroll
        for (int d = 0; d < 16; d++) {
            const float xv = Xs[tid * 17 + d];
            const float* gr = gate + (size_t)(dbase + d) * CE;  // wave-uniform
#pragma unroll
            for (int e = 0; e < CE; e++) acc[e] = fmaf(xv, gr[e], acc[e]);
        }
    }
    float* pr = part + ((size_t)dt * (CB * CS) + tt * 256 + tid) * CE;
#pragma unroll
    for (int e = 0; e < CE; e++) pr[e] = acc[e];
}

// ---------------- K1b: deterministic reduce of the 16 d-partials -------------
__global__ __launch_bounds__(256)
void logits_reduce_kernel(const float* __restrict__ part,
                          float* __restrict__ logits) {
    const int i = blockIdx.x * 256 + threadIdx.x;   // 0 .. B*S*E-1
    float s = 0.0f;
#pragma unroll
    for (int p = 0; p < 16; p++) s += part[(size_t)p * (CB * CS * CE) + i];
    logits[i] = s;
}

// ---------------- K2: per (b,e) softmax over tokens + top-256 ----------------
__global__ void topk_kernel(const float* __restrict__ logits,
                            int* __restrict__ idx_out,
                            float* __restrict__ g_out) {
    const int be = blockIdx.x;            // b*E + e
    const int b = be >> 4, e = be & 15;
    const int tid = threadIdx.x;          // 256
    const int lane = tid & 63, wid = tid >> 6;

    __shared__ float redf[4];
    __shared__ int hist[256];
    __shared__ int wsum[4];
    __shared__ int sh_bin, sh_rank;
    __shared__ int scnt, eqc;
    __shared__ int eqbuf[CS];

    float lv[8], p[8];
    unsigned int uv[8];
#pragma unroll
    for (int j = 0; j < 8; j++) {
        const int s = tid + j * 256;
        lv[j] = logits[((size_t)(b * CS + s)) * CE + e];
    }
    float m = lv[0];
#pragma unroll
    for (int j = 1; j < 8; j++) m = fmaxf(m, lv[j]);
#pragma unroll
    for (int o = 32; o > 0; o >>= 1) m = fmaxf(m, __shfl_down(m, o));
    if (lane == 0) redf[wid] = m;
    __syncthreads();
    m = fmaxf(fmaxf(redf[0], redf[1]), fmaxf(redf[2], redf[3]));
    __syncthreads();
    float lsum = 0.0f;
#pragma unroll
    for (int j = 0; j < 8; j++) {
        p[j] = expf(lv[j] - m);
        uv[j] = __float_as_uint(p[j]);
        lsum += p[j];
    }
#pragma unroll
    for (int o = 32; o > 0; o >>= 1) lsum += __shfl_down(lsum, o);
    if (lane == 0) redf[wid] = lsum;
    __syncthreads();
    const float total = redf[0] + redf[1] + redf[2] + redf[3];
    const float inv_total = 1.0f / total;

    // ---- radix-256 select: find v = CK-th largest bit pattern ----
    unsigned int prefix = 0;
    int kneed = CK;
    for (int pass = 0; pass < 4; pass++) {
        const int shift = 24 - 8 * pass;
        __syncthreads();
        hist[tid] = 0;
        __syncthreads();
        const unsigned int hmask = (pass == 0) ? 0u : (0xFFFFFFFFu << (shift + 8));
#pragma unroll
        for (int j = 0; j < 8; j++)
            if ((uv[j] & hmask) == prefix)
                atomicAdd(&hist[(uv[j] >> shift) & 255], 1);
        __syncthreads();
        const int own = hist[tid];
        int s = own;
#pragma unroll
        for (int o = 1; o < 64; o <<= 1) {
            int t = __shfl_down(s, o);
            if (lane + o < 64) s += t;
        }
        if (lane == 0) wsum[wid] = s;
        __syncthreads();
        int above = 0;
        for (int ww = wid + 1; ww < 4; ww++) above += wsum[ww];
        const int incl = s + above;
        if (incl >= kneed && (incl - own) < kneed) {
            sh_bin = tid;
            sh_rank = kneed - (incl - own);
        }
        __syncthreads();
        prefix |= ((unsigned int)sh_bin) << shift;
        kneed = sh_rank;
    }
    const unsigned int v = prefix;
    const int quota = kneed;

    if (tid == 0) { scnt = 0; eqc = 0; }
    __syncthreads();
#pragma unroll
    for (int j = 0; j < 8; j++) {
        const int s = tid + j * 256;
        if (uv[j] > v) {
            const int pos = atomicAdd(&scnt, 1);
            idx_out[be * CK + pos] = s;
            g_out[be * CK + pos] = p[j] * inv_total;
        } else if (uv[j] == v) {
            const int pos = atomicAdd(&eqc, 1);
            eqbuf[pos] = s;
        }
    }
    __syncthreads();
    if (tid == 0) {
        const int cgt = scnt;
        const int n = eqc;
        const float gv = __uint_as_float(v) * inv_total;
        if (n > quota) {
            for (int i = 0; i < quota; i++) {
                int mn = i;
                for (int k2 = i + 1; k2 < n; k2++)
                    if (eqbuf[k2] < eqbuf[mn]) mn = k2;
                const int t2 = eqbuf[i]; eqbuf[i] = eqbuf[mn]; eqbuf[mn] = t2;
            }
        }
        for (int i = 0; i < quota; i++) {
            idx_out[be * CK + cgt + i] = eqbuf[i];
            g_out[be * CK + cgt + i] = gv;
        }
    }
}

// ---------------- wt transpose body: W[e][k][n] fp32 -> Wt[e][n][k] bf16 -----
__device__ __forceinline__
void wt_body(const float* __restrict__ W, unsigned short* __restrict__ Wt,
             int kt, int nt, int e, int tid, unsigned short* T) {
    const float* src = W + (size_t)e * CD * CD;
    unsigned short* dst = Wt + (size_t)e * CD * CD;

    const int kr = tid >> 4;            // 0..15
    const int n4 = (tid & 15) << 2;     // 0,4,..,60
#pragma unroll
    for (int it = 0; it < 4; it++) {
        const int k = it * 16 + kr;                    // tile-local k 0..63
        const f32x4 v = *(const f32x4*)(src + (size_t)(kt * 64 + k) * CD + nt * 64 + n4);
        const int pp = k >> 4;                          // 16-short chunk 0..3
        const int klo = k & 15;
#pragma unroll
        for (int i = 0; i < 4; i++) {
            const int n = n4 + i;
            T[n * 64 + ((pp ^ ((n >> 2) & 3)) << 4) + klo] = f2bf(v[i]);
        }
    }
    __syncthreads();
    const int n = tid >> 2;             // 0..63
    const int pp = tid & 3;             // output k-chunk
    const int sw = pp ^ ((n >> 2) & 3);
    const uint4 a = *(const uint4*)&T[n * 64 + (sw << 4)];
    const uint4 b = *(const uint4*)&T[n * 64 + (sw << 4) + 8];
    unsigned short* drow = dst + (size_t)(nt * 64 + n) * CD + kt * 64 + pp * 16;
    *(uint4*)drow = a;
    *(uint4*)(drow + 8) = b;
}

__global__ __launch_bounds__(256)
void wt_kernel(const float* __restrict__ W, unsigned short* __restrict__ Wt) {
    __shared__ unsigned short T[64 * 64];
    wt_body(W, Wt, blockIdx.x, blockIdx.y, blockIdx.z, threadIdx.x, T);
}

// ---------------- prep: wt(W1) and gather fused (one launch) -----------------
__global__ __launch_bounds__(256)
void prep_kernel(const float* __restrict__ W1, unsigned short* __restrict__ Wt,
                 const float* __restrict__ x, const int* __restrict__ idx_ws,
                 unsigned short* __restrict__ xinbuf) {
    __shared__ unsigned short T[64 * 64];
    const int bx = blockIdx.x;
    if (bx < 4096) {
        wt_body(W1, Wt, bx & 15, (bx >> 4) & 15, bx >> 8, threadIdx.x, T);
    } else {
        const int row = bx - 4096;             // be*CK + slot
        const int be = row >> 8;
        const int b = be >> 4;
        const int tok = idx_ws[row];
        const int c0 = threadIdx.x * 4;
        const f32x4 f = *(const f32x4*)(x + ((size_t)b * CS + tok) * CD + c0);
        union { unsigned short u[4]; uint2 v; } t;
        t.u[0] = f2bf(f[0]); t.u[1] = f2bf(f[1]); t.u[2] = f2bf(f[2]); t.u[3] = f2bf(f[3]);
        *(uint2*)(xinbuf + (size_t)row * CD + c0) = t.v;
    }
}

// ---------------- touch: XCD-local L2 pre-warm for the GEMM inputs -----------
// Mirrors ffn_gemm's block->(b,e,ntile) decode exactly, so block i lands on the
// same XCD (id&7 round-robin) as gemm block i and pulls exactly the slabs that
// gemm block (and its XCD neighbors) will read into that XCD's L2. Touches
// unique bytes only: B (256KB) by b==0 blocks, A split by ntile (64KB each).
// B first, A second, so the 8x-re-read A survives LRU in the 4MB L2.
// Theory under test: real GEMMs are first-touch readers after the producer's
// end-of-kernel flush -> every tile stalls on ~L3-latency loads; pre-warmed L2
// (~200cyc) hides under the 2-deep pipeline's ~2100cyc/tile slack.
__global__ __launch_bounds__(256)
void touch_kernel(const unsigned short* __restrict__ Abuf,
                  const unsigned short* __restrict__ Bbuf,
                  float* __restrict__ scr) {
    const int id = blockIdx.x;            // 0..255, same decode as ffn_gemm
    const int xcd = id & 7;
    const int q = id >> 3;
    const int e = ((q & 1) << 3) | xcd;
    const int b = (q >> 1) & 1;
    const int ntile = q >> 2;             // 0..7
    const int be = b * CE + e;
    const int tid = threadIdx.x;

    float acc = 0.0f;
    if (b == 0) {
        // B slab for (e, ntile): 128 rows x 1024 k bf16 = 256 KB = 16384 uint4
        const uint4* pb = (const uint4*)(Bbuf + ((size_t)e * CD + ntile * 128) * CD);
#pragma unroll 8
        for (int i = tid; i < 16384; i += 256) {
            const uint4 v = pb[i];
            acc += (float)(v.x ^ v.w);
        }
    }
    // A share: rows [ntile*32, ntile*32+32) of the be-slab = 64 KB = 4096 uint4
    const uint4* pa = (const uint4*)(Abuf + ((size_t)be * CK + ntile * 32) * CD);
#pragma unroll 8
    for (int i = tid; i < 4096; i += 256) {
        const uint4 v = pa[i];
        acc += (float)(v.y);
    }
    scr[id * 256 + tid] = acc;   // keep all loads live (rule #17)
}

// ---------------- K5/K6: batched GEMM per (b,e) -- REG-STAGED ----------------
// BYTE-IDENTICAL to R5 (so dur_us deltas this round are attributable purely to
// the pre-warmed input cache state). Tile 256x128, BK=64, 8 waves 4(M)x2(N),
// XOR swizzle (u&7)^(row&7) on the global source with lane-linear LDS dest,
// 2-deep LDS double buffer (96 KB), one __syncthreads per K-tile.
#define MFMA16(A_, B_, C_) __builtin_amdgcn_mfma_f32_16x16x32_bf16((A_), (B_), (C_), 0, 0, 0)

template <int PHASE>
__global__ __launch_bounds__(512, 1)
void ffn_gemm(const unsigned short* __restrict__ Ain,
              const unsigned short* __restrict__ Wt,
              const float* __restrict__ bias,
              unsigned short* __restrict__ hout,
              const int* __restrict__ idx_ws,
              const float* __restrict__ g_ws,
              float* __restrict__ y) {
    const int id = blockIdx.x;            // 0..255
    const int xcd = id & 7;
    const int q = id >> 3;                // 0..31
    const int e = ((q & 1) << 3) | xcd;
    const int b = (q >> 1) & 1;
    const int ntile = q >> 2;             // 0..7
    const int be = b * CE + e;
    const int tid = threadIdx.x;
    const int w = tid >> 6, l = tid & 63;
    const int wm = w >> 1, wn = w & 1;    // wave grid 4(M) x 2(N)
    const int quad = l >> 4, lr = l & 15;

    __shared__ __align__(16) unsigned short LA[2][256 * 64];   // 2 x 32 KB
    __shared__ __align__(16) unsigned short LB[2][128 * 64];   // 2 x 16 KB

    f32x4 acc[4][4];
    const f32x4 zz = {0.f, 0.f, 0.f, 0.f};
#pragma unroll
    for (int mi = 0; mi < 4; mi++)
#pragma unroll
        for (int ni = 0; ni < 4; ni++) acc[mi][ni] = zz;

    const unsigned short* Agb = Ain + (size_t)be * CK * CD;                 // [256][1024]
    const unsigned short* Bgb = Wt + ((size_t)e * CD + ntile * 128) * CD;   // [128][1024]

    // staging geometry: unit u = one 16B chunk of the LDS tile. LDS dest is
    // lane-linear; global chunk c = (u&7) ^ (row&7)  (both-sides swizzle).
    const unsigned short* pAg[4]; int dA[4];
#pragma unroll
    for (int j = 0; j < 4; j++) {
        const int u = w * 256 + j * 64 + l;      // 0..2047
        const int row = u >> 3;
        const int c = (u & 7) ^ (row & 7);
        pAg[j] = Agb + (size_t)row * CD + c * 8;
        dA[j] = u * 8;
    }
    const unsigned short* pBg[2]; int dB[2];
#pragma unroll
    for (int j = 0; j < 2; j++) {
        const int u = w * 128 + j * 64 + l;      // 0..1023
        const int row = u >> 3;
        const int c = (u & 7) ^ (row & 7);
        pBg[j] = Bgb + (size_t)row * CD + c * 8;
        dB[j] = u * 8;
    }

    // fragment read offsets (ushort units): row*64 + ((kk*4+quad)^(row&7))*8
    const int sc0 = (quad ^ (lr & 7)) * 8;
    const int sc1 = sc0 ^ 32;
    int offA[2][4], offB[2][4];
#pragma unroll
    for (int mi = 0; mi < 4; mi++) {
        const int r = wm * 64 + mi * 16 + lr;
        offA[0][mi] = r * 64 + sc0;
        offA[1][mi] = r * 64 + sc1;
    }
#pragma unroll
    for (int ni = 0; ni < 4; ni++) {
        const int r = wn * 64 + ni * 16 + lr;
        offB[0][ni] = r * 64 + sc0;
        offB[1][ni] = r * 64 + sc1;
    }

    unsigned short* Ar = (unsigned short*)LA[0];
    unsigned short* Aw = (unsigned short*)LA[1];
    unsigned short* Br = (unsigned short*)LB[0];
    unsigned short* Bw = (unsigned short*)LB[1];

    // preload tile 0: global -> regs -> LDS buf0
    bf16x8 sA0, sA1, sA2, sA3, sB0, sB1;
    sA0 = *(const bf16x8*)(pAg[0]); sA1 = *(const bf16x8*)(pAg[1]);
    sA2 = *(const bf16x8*)(pAg[2]); sA3 = *(const bf16x8*)(pAg[3]);
    sB0 = *(const bf16x8*)(pBg[0]); sB1 = *(const bf16x8*)(pBg[1]);
    *(bf16x8*)(Ar + dA[0]) = sA0; *(bf16x8*)(Ar + dA[1]) = sA1;
    *(bf16x8*)(Ar + dA[2]) = sA2; *(bf16x8*)(Ar + dA[3]) = sA3;
    *(bf16x8*)(Br + dB[0]) = sB0; *(bf16x8*)(Br + dB[1]) = sB1;
    __syncthreads();

#pragma unroll 1
    for (int t = 0; t < 16; t++) {
        // issue next-tile loads early; vmcnt waits land before the ds_write use
        if (t < 15) {
            const int kel = (t + 1) * 64;
            sA0 = *(const bf16x8*)(pAg[0] + kel);
            sA1 = *(const bf16x8*)(pAg[1] + kel);
            sA2 = *(const bf16x8*)(pAg[2] + kel);
            sA3 = *(const bf16x8*)(pAg[3] + kel);
            sB0 = *(const bf16x8*)(pBg[0] + kel);
            sB1 = *(const bf16x8*)(pBg[1] + kel);
        }
        bf16x8 a0, a1, a2, a3, b0, b1, b2, b3;
#pragma unroll
        for (int kk = 0; kk < 2; kk++) {
            a0 = ds_read128((lds_us*)Ar + offA[kk][0]);
            a1 = ds_read128((lds_us*)Ar + offA[kk][1]);
            a2 = ds_read128((lds_us*)Ar + offA[kk][2]);
            a3 = ds_read128((lds_us*)Ar + offA[kk][3]);
            b0 = ds_read128((lds_us*)Br + offB[kk][0]);
            b1 = ds_read128((lds_us*)Br + offB[kk][1]);
            b2 = ds_read128((lds_us*)Br + offB[kk][2]);
            b3 = ds_read128((lds_us*)Br + offB[kk][3]);
            asm volatile("s_waitcnt lgkmcnt(0)"
                         : "+v"(a0), "+v"(a1), "+v"(a2), "+v"(a3),
                           "+v"(b0), "+v"(b1), "+v"(b2), "+v"(b3) :: "memory");
            __builtin_amdgcn_s_setprio(1);
            acc[0][0] = MFMA16(a0, b0, acc[0][0]);
            acc[1][0] = MFMA16(a1, b0, acc[1][0]);
            acc[2][0] = MFMA16(a2, b0, acc[2][0]);
            acc[3][0] = MFMA16(a3, b0, acc[3][0]);
            acc[0][1] = MFMA16(a0, b1, acc[0][1]);
            acc[1][1] = MFMA16(a1, b1, acc[1][1]);
            acc[2][1] = MFMA16(a2, b1, acc[2][1]);
            acc[3][1] = MFMA16(a3, b1, acc[3][1]);
            acc[0][2] = MFMA16(a0, b2, acc[0][2]);
            acc[1][2] = MFMA16(a1, b2, acc[1][2]);
            acc[2][2] = MFMA16(a2, b2, acc[2][2]);
            acc[3][2] = MFMA16(a3, b2, acc[3][2]);
            acc[0][3] = MFMA16(a0, b3, acc[0][3]);
            acc[1][3] = MFMA16(a1, b3, acc[1][3]);
            acc[2][3] = MFMA16(a2, b3, acc[2][3]);
            acc[3][3] = MFMA16(a3, b3, acc[3][3]);
            __builtin_amdgcn_s_setprio(0);
        }
        if (t < 15) {
            // write tile t+1 into the non-read buffer; all waves finished their
            // tile-t ds_reads before their own MFMAs, so one barrier suffices.
            *(bf16x8*)(Aw + dA[0]) = sA0; *(bf16x8*)(Aw + dA[1]) = sA1;
            *(bf16x8*)(Aw + dA[2]) = sA2; *(bf16x8*)(Aw + dA[3]) = sA3;
            *(bf16x8*)(Bw + dB[0]) = sB0; *(bf16x8*)(Bw + dB[1]) = sB1;
            __syncthreads();
            unsigned short* tp = Ar; Ar = Aw; Aw = tp;
            tp = Br; Br = Bw; Bw = tp;
        }
    }

    // epilogue. C/D layout: col = lane&15, row = quad*4 + r  (m89/m91 verified)
    const int gn_base = ntile * 128 + wn * 64;
    if (PHASE == 0) {
#pragma unroll
        for (int mi = 0; mi < 4; mi++)
#pragma unroll
            for (int r = 0; r < 4; r++) {
                const int slot = wm * 64 + mi * 16 + quad * 4 + r;
                unsigned short* outrow = hout + ((size_t)be * CK + slot) * CD;
#pragma unroll
                for (int ni = 0; ni < 4; ni++) {
                    const int col = gn_base + ni * 16 + lr;
                    float hv = acc[mi][ni][r] + bias[e * CD + col];
                    hv = fmaxf(hv, 0.0f);
                    outrow[col] = f2bf(hv);
                }
            }
    } else {
#pragma unroll
        for (int mi = 0; mi < 4; mi++)
#pragma unroll
            for (int r = 0; r < 4; r++) {
                const int slot = wm * 64 + mi * 16 + quad * 4 + r;
                const int tok = idx_ws[be * CK + slot];
                const float gval = g_ws[be * CK + slot];
                float* yrow = y + ((size_t)b * CS + tok) * CD;
#pragma unroll
                for (int ni = 0; ni < 4; ni++) {
                    const int col = gn_base + ni * 16 + lr;
                    const float val = (acc[mi][ni][r] + bias[col]) * gval;
                    atomicAdd(&yrow[col], val);
                }
            }
    }
}

extern "C" void kernel_launch(void* const* d_in, const int* in_sizes, int n_in,
                              void* d_out, int out_size, void* d_ws, size_t ws_size,
                              hipStream_t stream) {
    const float* x    = (const float*)d_in[0];
    const float* gate = (const float*)d_in[1];
    const float* W1   = (const float*)d_in[2];
    const float* b1   = (const float*)d_in[3];
    const float* W2   = (const float*)d_in[4];
    const float* b2   = (const float*)d_in[5];
    float* y = (float*)d_out;

    // workspace layout (bytes):
    //   logits: 0         .. 262144     (B*S*E fp32) [reused as touch scratch
    //                                    after topk consumes it: 256KB exactly]
    //   idx:    262144    .. +32768
    //   g:      294912    .. +32768
    //   xin:    327680    .. +16.78MB   (bf16)
    //   hbuf:   17104896  .. +16.78MB   (bf16)  [aliased: logits partials 4MB]
    //   Wt:     33882112  .. +33.55MB   (bf16, W1 then reused for W2)
    char* ws = (char*)d_ws;
    float* logits = (float*)ws;
    int* idxw = (int*)(ws + 262144);
    float* gw = (float*)(ws + 294912);
    unsigned short* xinbuf = (unsigned short*)(ws + 327680);
    unsigned short* hbuf = (unsigned short*)(ws + 17104896);
    float* partbuf = (float*)(ws + 17104896);   // lifetime disjoint from hbuf
    unsigned short* wtbuf = (unsigned short*)(ws + 33882112);
    float* tscr = (float*)ws;                   // logits region, dead after topk

    logits_part_kernel<<<dim3(16, 16), 256, 0, stream>>>(x, gate, partbuf, y);
    logits_reduce_kernel<<<CB * CS * CE / 256, 256, 0, stream>>>(partbuf, logits);
    topk_kernel<<<CB * CE, 256, 0, stream>>>(logits, idxw, gw);
    prep_kernel<<<4096 + CB * CE * CK, 256, 0, stream>>>(W1, wtbuf, x, idxw, xinbuf);
    touch_kernel<<<256, 256, 0, stream>>>(xinbuf, wtbuf, tscr);
    ffn_gemm<0><<<256, 512, 0, stream>>>(xinbuf, wtbuf, b1, hbuf, idxw, gw, y);
    wt_kernel<<<dim3(16, 16, CE), 256, 0, stream>>>(W2, wtbuf);
    touch_kernel<<<256, 256, 0, stream>>>(hbuf, wtbuf, tscr);
    ffn_gemm<1><<<256, 512, 0, stream>>>(hbuf, wtbuf, b2, nullptr, idxw, gw, y);
}

// Round 8
// 276.336 us; speedup vs baseline: 1.0754x; 1.0754x over previous
//
#include <hip/hip_runtime.h>
#include <stdint.h>
#include <math.h>

// Problem constants (fixed by the reference)
constexpr int CB = 2;      // batch
constexpr int CS = 2048;   // seq (cutoff)
constexpr int CD = 1024;   // dmodel
constexpr int CE = 16;     // experts
constexpr int CK = 256;    // topk

typedef short bf16x8 __attribute__((ext_vector_type(8)));
typedef float f32x4 __attribute__((ext_vector_type(4)));

typedef __attribute__((address_space(3))) unsigned short lds_us;

// ds_read_b128 hidden from the waitcnt legalizer; ordering vs MFMA is enforced
// by the "+v" register ties on the explicit lgkmcnt asm (ties = data dep).
__device__ __forceinline__ bf16x8 ds_read128(const lds_us* p) {
    bf16x8 v;
    asm volatile("ds_read_b128 %0, %1" : "=v"(v) : "v"(p));
    return v;
}

__device__ inline unsigned short f2bf(float f) {
    union { float f; uint32_t u; } v; v.f = f;
    uint32_t u = v.u;
    uint32_t r = (u + 0x7FFFu + ((u >> 16) & 1u)) >> 16;
    return (unsigned short)r;
}

// ---------------- K1a: partial logits over a 64-d slice (+ zero y) ----------
__global__ __launch_bounds__(256)
void logits_part_kernel(const float* __restrict__ x,
                        const float* __restrict__ gate,
                        float* __restrict__ part,
                        float* __restrict__ y) {
    const int tt = blockIdx.x;       // token tile (256 tokens)
    const int dt = blockIdx.y;       // d tile (64 d)
    const int tid = threadIdx.x;

    // fold the y-zeroing in here (saves a hipMemsetAsync launch node).
    {
        const int bb = dt * 16 + tt;
        float* yb = y + (size_t)bb * 16384 + tid * 4;
        const f32x4 z = {0.f, 0.f, 0.f, 0.f};
#pragma unroll
        for (int i = 0; i < 16; i++) *(f32x4*)(yb + i * 1024) = z;
    }

    __shared__ float Xs[256 * 17];

    float acc[CE];
#pragma unroll
    for (int e = 0; e < CE; e++) acc[e] = 0.0f;

    const int tokl = tid >> 2;           // staging row within 64-token group
    const int c4 = (tid & 3) << 2;       // staging col (0,4,8,12)

    for (int dch = 0; dch < 4; dch++) {
        const int dbase = dt * 64 + dch * 16;
        __syncthreads();
#pragma unroll
        for (int q = 0; q < 4; q++) {
            const int tok = q * 64 + tokl;
            const f32x4 v = *(const f32x4*)(x + ((size_t)(tt * 256 + tok)) * CD + dbase + c4);
            Xs[tok * 17 + c4 + 0] = v[0];
            Xs[tok * 17 + c4 + 1] = v[1];
            Xs[tok * 17 + c4 + 2] = v[2];
            Xs[tok * 17 + c4 + 3] = v[3];
        }
        __syncthreads();
#pragma unroll
        for (int d = 0; d < 16; d++) {
            const float xv = Xs[tid * 17 + d];
            const float* gr = gate + (size_t)(dbase + d) * CE;  // wave-uniform
#pragma unroll
            for (int e = 0; e < CE; e++) acc[e] = fmaf(xv, gr[e], acc[e]);
        }
    }
    float* pr = part + ((size_t)dt * (CB * CS) + tt * 256 + tid) * CE;
#pragma unroll
    for (int e = 0; e < CE; e++) pr[e] = acc[e];
}

// ---------------- K1b: deterministic reduce of the 16 d-partials -------------
__global__ __launch_bounds__(256)
void logits_reduce_kernel(const float* __restrict__ part,
                          float* __restrict__ logits) {
    const int i = blockIdx.x * 256 + threadIdx.x;   // 0 .. B*S*E-1
    float s = 0.0f;
#pragma unroll
    for (int p = 0; p < 16; p++) s += part[(size_t)p * (CB * CS * CE) + i];
    logits[i] = s;
}

// ---------------- K2: per (b,e) softmax over tokens + top-256 ----------------
__global__ void topk_kernel(const float* __restrict__ logits,
                            int* __restrict__ idx_out,
                            float* __restrict__ g_out) {
    const int be = blockIdx.x;            // b*E + e
    const int b = be >> 4, e = be & 15;
    const int tid = threadIdx.x;          // 256
    const int lane = tid & 63, wid = tid >> 6;

    __shared__ float redf[4];
    __shared__ int hist[256];
    __shared__ int wsum[4];
    __shared__ int sh_bin, sh_rank;
    __shared__ int scnt, eqc;
    __shared__ int eqbuf[CS];

    float lv[8], p[8];
    unsigned int uv[8];
#pragma unroll
    for (int j = 0; j < 8; j++) {
        const int s = tid + j * 256;
        lv[j] = logits[((size_t)(b * CS + s)) * CE + e];
    }
    float m = lv[0];
#pragma unroll
    for (int j = 1; j < 8; j++) m = fmaxf(m, lv[j]);
#pragma unroll
    for (int o = 32; o > 0; o >>= 1) m = fmaxf(m, __shfl_down(m, o));
    if (lane == 0) redf[wid] = m;
    __syncthreads();
    m = fmaxf(fmaxf(redf[0], redf[1]), fmaxf(redf[2], redf[3]));
    __syncthreads();
    float lsum = 0.0f;
#pragma unroll
    for (int j = 0; j < 8; j++) {
        p[j] = expf(lv[j] - m);
        uv[j] = __float_as_uint(p[j]);
        lsum += p[j];
    }
#pragma unroll
    for (int o = 32; o > 0; o >>= 1) lsum += __shfl_down(lsum, o);
    if (lane == 0) redf[wid] = lsum;
    __syncthreads();
    const float total = redf[0] + redf[1] + redf[2] + redf[3];
    const float inv_total = 1.0f / total;

    // ---- radix-256 select: find v = CK-th largest bit pattern ----
    unsigned int prefix = 0;
    int kneed = CK;
    for (int pass = 0; pass < 4; pass++) {
        const int shift = 24 - 8 * pass;
        __syncthreads();
        hist[tid] = 0;
        __syncthreads();
        const unsigned int hmask = (pass == 0) ? 0u : (0xFFFFFFFFu << (shift + 8));
#pragma unroll
        for (int j = 0; j < 8; j++)
            if ((uv[j] & hmask) == prefix)
                atomicAdd(&hist[(uv[j] >> shift) & 255], 1);
        __syncthreads();
        const int own = hist[tid];
        int s = own;
#pragma unroll
        for (int o = 1; o < 64; o <<= 1) {
            int t = __shfl_down(s, o);
            if (lane + o < 64) s += t;
        }
        if (lane == 0) wsum[wid] = s;
        __syncthreads();
        int above = 0;
        for (int ww = wid + 1; ww < 4; ww++) above += wsum[ww];
        const int incl = s + above;
        if (incl >= kneed && (incl - own) < kneed) {
            sh_bin = tid;
            sh_rank = kneed - (incl - own);
        }
        __syncthreads();
        prefix |= ((unsigned int)sh_bin) << shift;
        kneed = sh_rank;
    }
    const unsigned int v = prefix;
    const int quota = kneed;

    if (tid == 0) { scnt = 0; eqc = 0; }
    __syncthreads();
#pragma unroll
    for (int j = 0; j < 8; j++) {
        const int s = tid + j * 256;
        if (uv[j] > v) {
            const int pos = atomicAdd(&scnt, 1);
            idx_out[be * CK + pos] = s;
            g_out[be * CK + pos] = p[j] * inv_total;
        } else if (uv[j] == v) {
            const int pos = atomicAdd(&eqc, 1);
            eqbuf[pos] = s;
        }
    }
    __syncthreads();
    if (tid == 0) {
        const int cgt = scnt;
        const int n = eqc;
        const float gv = __uint_as_float(v) * inv_total;
        if (n > quota) {
            for (int i = 0; i < quota; i++) {
                int mn = i;
                for (int k2 = i + 1; k2 < n; k2++)
                    if (eqbuf[k2] < eqbuf[mn]) mn = k2;
                const int t2 = eqbuf[i]; eqbuf[i] = eqbuf[mn]; eqbuf[mn] = t2;
            }
        }
        for (int i = 0; i < quota; i++) {
            idx_out[be * CK + cgt + i] = eqbuf[i];
            g_out[be * CK + cgt + i] = gv;
        }
    }
}

// ---------------- wt transpose body: W[e][k][n] fp32 -> Wt[e][n][k] bf16 -----
__device__ __forceinline__
void wt_body(const float* __restrict__ W, unsigned short* __restrict__ Wt,
             int kt, int nt, int e, int tid, unsigned short* T) {
    const float* src = W + (size_t)e * CD * CD;
    unsigned short* dst = Wt + (size_t)e * CD * CD;

    const int kr = tid >> 4;            // 0..15
    const int n4 = (tid & 15) << 2;     // 0,4,..,60
#pragma unroll
    for (int it = 0; it < 4; it++) {
        const int k = it * 16 + kr;                    // tile-local k 0..63
        const f32x4 v = *(const f32x4*)(src + (size_t)(kt * 64 + k) * CD + nt * 64 + n4);
        const int pp = k >> 4;                          // 16-short chunk 0..3
        const int klo = k & 15;
#pragma unroll
        for (int i = 0; i < 4; i++) {
            const int n = n4 + i;
            T[n * 64 + ((pp ^ ((n >> 2) & 3)) << 4) + klo] = f2bf(v[i]);
        }
    }
    __syncthreads();
    const int n = tid >> 2;             // 0..63
    const int pp = tid & 3;             // output k-chunk
    const int sw = pp ^ ((n >> 2) & 3);
    const uint4 a = *(const uint4*)&T[n * 64 + (sw << 4)];
    const uint4 b = *(const uint4*)&T[n * 64 + (sw << 4) + 8];
    unsigned short* drow = dst + (size_t)(nt * 64 + n) * CD + kt * 64 + pp * 16;
    *(uint4*)drow = a;
    *(uint4*)(drow + 8) = b;
}

__global__ __launch_bounds__(256)
void wt_kernel(const float* __restrict__ W, unsigned short* __restrict__ Wt) {
    __shared__ unsigned short T[64 * 64];
    wt_body(W, Wt, blockIdx.x, blockIdx.y, blockIdx.z, threadIdx.x, T);
}

// ---------------- prep: wt(W1) and gather fused (one launch) -----------------
__global__ __launch_bounds__(256)
void prep_kernel(const float* __restrict__ W1, unsigned short* __restrict__ Wt,
                 const float* __restrict__ x, const int* __restrict__ idx_ws,
                 unsigned short* __restrict__ xinbuf) {
    __shared__ unsigned short T[64 * 64];
    const int bx = blockIdx.x;
    if (bx < 4096) {
        wt_body(W1, Wt, bx & 15, (bx >> 4) & 15, bx >> 8, threadIdx.x, T);
    } else {
        const int row = bx - 4096;             // be*CK + slot
        const int be = row >> 8;
        const int b = be >> 4;
        const int tok = idx_ws[row];
        const int c0 = threadIdx.x * 4;
        const f32x4 f = *(const f32x4*)(x + ((size_t)b * CS + tok) * CD + c0);
        union { unsigned short u[4]; uint2 v; } t;
        t.u[0] = f2bf(f[0]); t.u[1] = f2bf(f[1]); t.u[2] = f2bf(f[2]); t.u[3] = f2bf(f[3]);
        *(uint2*)(xinbuf + (size_t)row * CD + c0) = t.v;
    }
}

// ---------------- K5/K6: batched GEMM per (b,e) -- REG-STAGED ----------------
// Main loop byte-equivalent to R5 (invariant at ~49us across R0-R6; probe-proven
// ~14-16us alone). CHANGED (vs R5/R6): the epilogue. Old epilogue issued 8.4M
// fine-grain ops/dispatch (64x scalar 2B stores or f32 atomics per thread,
// only 32B contiguous per quad) -> WRITE_SIZE showed 32MB for a 16MB buffer
// (2x partial-line RMW). New epilogue: dump acc into the (now dead) staging
// LDS as a 128x133-padded f32 tile (2 halves), then drain with full-line
// writes: PHASE0 = uint4 bf16 stores (256B-aligned, 256B/row contiguous);
// PHASE1 = 64-lane-contiguous f32 atomics (256B/instr merged).
#define MFMA16(A_, B_, C_) __builtin_amdgcn_mfma_f32_16x16x32_bf16((A_), (B_), (C_), 0, 0, 0)

template <int PHASE>
__global__ __launch_bounds__(512, 1)
void ffn_gemm(const unsigned short* __restrict__ Ain,
              const unsigned short* __restrict__ Wt,
              const float* __restrict__ bias,
              unsigned short* __restrict__ hout,
              const int* __restrict__ idx_ws,
              const float* __restrict__ g_ws,
              float* __restrict__ y) {
    const int id = blockIdx.x;            // 0..255
    const int xcd = id & 7;
    const int q = id >> 3;                // 0..31
    const int e = ((q & 1) << 3) | xcd;
    const int b = (q >> 1) & 1;
    const int ntile = q >> 2;             // 0..7
    const int be = b * CE + e;
    const int tid = threadIdx.x;
    const int w = tid >> 6, l = tid & 63;
    const int wm = w >> 1, wn = w & 1;    // wave grid 4(M) x 2(N)
    const int quad = l >> 4, lr = l & 15;

    // 96KB carved: Ar(32K) Aw(32K) Br(16K) Bw(16K); epilogue reuses as
    // 128x133 f32 transpose tile (68KB).
    __shared__ __align__(16) unsigned char SMEM[98304];
    unsigned short* Ar = (unsigned short*)SMEM;            // 16384 ushorts
    unsigned short* Aw = Ar + 16384;
    unsigned short* Br = Aw + 16384;                       // 8192 ushorts
    unsigned short* Bw = Br + 8192;

    f32x4 acc[4][4];
    const f32x4 zz = {0.f, 0.f, 0.f, 0.f};
#pragma unroll
    for (int mi = 0; mi < 4; mi++)
#pragma unroll
        for (int ni = 0; ni < 4; ni++) acc[mi][ni] = zz;

    const unsigned short* Agb = Ain + (size_t)be * CK * CD;                 // [256][1024]
    const unsigned short* Bgb = Wt + ((size_t)e * CD + ntile * 128) * CD;   // [128][1024]

    // staging geometry: unit u = one 16B chunk of the LDS tile. LDS dest is
    // lane-linear; global chunk c = (u&7) ^ (row&7)  (both-sides swizzle).
    const unsigned short* pAg[4]; int dA[4];
#pragma unroll
    for (int j = 0; j < 4; j++) {
        const int u = w * 256 + j * 64 + l;      // 0..2047
        const int row = u >> 3;
        const int c = (u & 7) ^ (row & 7);
        pAg[j] = Agb + (size_t)row * CD + c * 8;
        dA[j] = u * 8;
    }
    const unsigned short* pBg[2]; int dB[2];
#pragma unroll
    for (int j = 0; j < 2; j++) {
        const int u = w * 128 + j * 64 + l;      // 0..1023
        const int row = u >> 3;
        const int c = (u & 7) ^ (row & 7);
        pBg[j] = Bgb + (size_t)row * CD + c * 8;
        dB[j] = u * 8;
    }

    // fragment read offsets (ushort units): row*64 + ((kk*4+quad)^(row&7))*8
    const int sc0 = (quad ^ (lr & 7)) * 8;
    const int sc1 = sc0 ^ 32;
    int offA[2][4], offB[2][4];
#pragma unroll
    for (int mi = 0; mi < 4; mi++) {
        const int r = wm * 64 + mi * 16 + lr;
        offA[0][mi] = r * 64 + sc0;
        offA[1][mi] = r * 64 + sc1;
    }
#pragma unroll
    for (int ni = 0; ni < 4; ni++) {
        const int r = wn * 64 + ni * 16 + lr;
        offB[0][ni] = r * 64 + sc0;
        offB[1][ni] = r * 64 + sc1;
    }

    // preload tile 0: global -> regs -> LDS buf0
    bf16x8 sA0, sA1, sA2, sA3, sB0, sB1;
    sA0 = *(const bf16x8*)(pAg[0]); sA1 = *(const bf16x8*)(pAg[1]);
    sA2 = *(const bf16x8*)(pAg[2]); sA3 = *(const bf16x8*)(pAg[3]);
    sB0 = *(const bf16x8*)(pBg[0]); sB1 = *(const bf16x8*)(pBg[1]);
    *(bf16x8*)(Ar + dA[0]) = sA0; *(bf16x8*)(Ar + dA[1]) = sA1;
    *(bf16x8*)(Ar + dA[2]) = sA2; *(bf16x8*)(Ar + dA[3]) = sA3;
    *(bf16x8*)(Br + dB[0]) = sB0; *(bf16x8*)(Br + dB[1]) = sB1;
    __syncthreads();

#pragma unroll 1
    for (int t = 0; t < 16; t++) {
        // issue next-tile loads early; vmcnt waits land before the ds_write use
        if (t < 15) {
            const int kel = (t + 1) * 64;
            sA0 = *(const bf16x8*)(pAg[0] + kel);
            sA1 = *(const bf16x8*)(pAg[1] + kel);
            sA2 = *(const bf16x8*)(pAg[2] + kel);
            sA3 = *(const bf16x8*)(pAg[3] + kel);
            sB0 = *(const bf16x8*)(pBg[0] + kel);
            sB1 = *(const bf16x8*)(pBg[1] + kel);
        }
        bf16x8 a0, a1, a2, a3, b0, b1, b2, b3;
#pragma unroll
        for (int kk = 0; kk < 2; kk++) {
            a0 = ds_read128((lds_us*)Ar + offA[kk][0]);
            a1 = ds_read128((lds_us*)Ar + offA[kk][1]);
            a2 = ds_read128((lds_us*)Ar + offA[kk][2]);
            a3 = ds_read128((lds_us*)Ar + offA[kk][3]);
            b0 = ds_read128((lds_us*)Br + offB[kk][0]);
            b1 = ds_read128((lds_us*)Br + offB[kk][1]);
            b2 = ds_read128((lds_us*)Br + offB[kk][2]);
            b3 = ds_read128((lds_us*)Br + offB[kk][3]);
            asm volatile("s_waitcnt lgkmcnt(0)"
                         : "+v"(a0), "+v"(a1), "+v"(a2), "+v"(a3),
                           "+v"(b0), "+v"(b1), "+v"(b2), "+v"(b3) :: "memory");
            __builtin_amdgcn_s_setprio(1);
            acc[0][0] = MFMA16(a0, b0, acc[0][0]);
            acc[1][0] = MFMA16(a1, b0, acc[1][0]);
            acc[2][0] = MFMA16(a2, b0, acc[2][0]);
            acc[3][0] = MFMA16(a3, b0, acc[3][0]);
            acc[0][1] = MFMA16(a0, b1, acc[0][1]);
            acc[1][1] = MFMA16(a1, b1, acc[1][1]);
            acc[2][1] = MFMA16(a2, b1, acc[2][1]);
            acc[3][1] = MFMA16(a3, b1, acc[3][1]);
            acc[0][2] = MFMA16(a0, b2, acc[0][2]);
            acc[1][2] = MFMA16(a1, b2, acc[1][2]);
            acc[2][2] = MFMA16(a2, b2, acc[2][2]);
            acc[3][2] = MFMA16(a3, b2, acc[3][2]);
            acc[0][3] = MFMA16(a0, b3, acc[0][3]);
            acc[1][3] = MFMA16(a1, b3, acc[1][3]);
            acc[2][3] = MFMA16(a2, b3, acc[2][3]);
            acc[3][3] = MFMA16(a3, b3, acc[3][3]);
            __builtin_amdgcn_s_setprio(0);
        }
        if (t < 15) {
            *(bf16x8*)(Aw + dA[0]) = sA0; *(bf16x8*)(Aw + dA[1]) = sA1;
            *(bf16x8*)(Aw + dA[2]) = sA2; *(bf16x8*)(Aw + dA[3]) = sA3;
            *(bf16x8*)(Bw + dB[0]) = sB0; *(bf16x8*)(Bw + dB[1]) = sB1;
            __syncthreads();
            unsigned short* tp = Ar; Ar = Aw; Aw = tp;
            tp = Br; Br = Bw; Bw = tp;
        }
    }

    // ---- epilogue: LDS transpose -> full-line writes ----
    // acc layout per thread: row_local = wm*64+mi*16+quad*4+r, col = wn*64+ni*16+lr.
    // Two halves of 128 rows; LT pitch 133 (=5 mod 32) keeps drain reads ~conflict-free.
    __syncthreads();                       // staging buffers dead from here
    float* LT = (float*)SMEM;              // 128 x 133 f32 = 68 KB
#pragma unroll 1
    for (int h = 0; h < 2; h++) {
        if ((wm >> 1) == h) {
            const int rb = (wm & 1) * 64;
#pragma unroll
            for (int mi = 0; mi < 4; mi++)
#pragma unroll
                for (int ni = 0; ni < 4; ni++)
#pragma unroll
                    for (int r = 0; r < 4; r++)
                        LT[(rb + mi * 16 + quad * 4 + r) * 133 + wn * 64 + ni * 16 + lr] =
                            acc[mi][ni][r];
        }
        __syncthreads();
        if (PHASE == 0) {
            // wave w drains rows w*16..w*16+15; 4 rows per pass, 16 lanes/row,
            // 16B bf16 store per lane -> 256B contiguous per row, 256B-aligned.
#pragma unroll
            for (int rr = 0; rr < 4; rr++) {
                const int row = w * 16 + rr * 4 + (l >> 4);
                const int col = (l & 15) * 8;
                const int slot = h * 128 + row;
                const float* lrow = LT + row * 133 + col;
                const float* brow = bias + e * CD + ntile * 128 + col;
                union { unsigned short us[8]; uint4 v; } pk;
#pragma unroll
                for (int i = 0; i < 8; i++)
                    pk.us[i] = f2bf(fmaxf(lrow[i] + brow[i], 0.0f));
                *(uint4*)(hout + ((size_t)be * CK + slot) * CD + ntile * 128 + col) = pk.v;
            }
        } else {
            // wave w drains 16 rows, one row at a time: 64 lanes contiguous
            // f32 atomics (2 per lane) -> 256B merged per instruction.
#pragma unroll 1
            for (int rr = 0; rr < 16; rr++) {
                const int row = w * 16 + rr;
                const int slot = h * 128 + row;
                const int tok = idx_ws[be * CK + slot];
                const float gval = g_ws[be * CK + slot];
                float* yrow = y + ((size_t)b * CS + tok) * CD + ntile * 128;
                const float* lrow = LT + row * 133;
                const float* brow = bias + ntile * 128;
#pragma unroll
                for (int i = 0; i < 2; i++) {
                    const int col = i * 64 + l;
                    atomicAdd(&yrow[col], (lrow[col] + brow[col]) * gval);
                }
            }
        }
        __syncthreads();
    }
}

extern "C" void kernel_launch(void* const* d_in, const int* in_sizes, int n_in,
                              void* d_out, int out_size, void* d_ws, size_t ws_size,
                              hipStream_t stream) {
    const float* x    = (const float*)d_in[0];
    const float* gate = (const float*)d_in[1];
    const float* W1   = (const float*)d_in[2];
    const float* b1   = (const float*)d_in[3];
    const float* W2   = (const float*)d_in[4];
    const float* b2   = (const float*)d_in[5];
    float* y = (float*)d_out;

    // workspace layout (bytes):
    //   logits: 0         .. 262144     (B*S*E fp32)
    //   idx:    262144    .. +32768
    //   g:      294912    .. +32768
    //   xin:    327680    .. +16.78MB   (bf16)
    //   hbuf:   17104896  .. +16.78MB   (bf16)  [aliased: logits partials 4MB]
    //   Wt:     33882112  .. +33.55MB   (bf16, W1 then reused for W2)
    char* ws = (char*)d_ws;
    float* logits = (float*)ws;
    int* idxw = (int*)(ws + 262144);
    float* gw = (float*)(ws + 294912);
    unsigned short* xinbuf = (unsigned short*)(ws + 327680);
    unsigned short* hbuf = (unsigned short*)(ws + 17104896);
    float* partbuf = (float*)(ws + 17104896);   // lifetime disjoint from hbuf
    unsigned short* wtbuf = (unsigned short*)(ws + 33882112);

    logits_part_kernel<<<dim3(16, 16), 256, 0, stream>>>(x, gate, partbuf, y);
    logits_reduce_kernel<<<CB * CS * CE / 256, 256, 0, stream>>>(partbuf, logits);
    topk_kernel<<<CB * CE, 256, 0, stream>>>(logits, idxw, gw);
    prep_kernel<<<4096 + CB * CE * CK, 256, 0, stream>>>(W1, wtbuf, x, idxw, xinbuf);
    ffn_gemm<0><<<256, 512, 0, stream>>>(xinbuf, wtbuf, b1, hbuf, idxw, gw, y);
    wt_kernel<<<dim3(16, 16, CE), 256, 0, stream>>>(W2, wtbuf);
    ffn_gemm<1><<<256, 512, 0, stream>>>(hbuf, wtbuf, b2, nullptr, idxw, gw, y);
}

// Round 9
// 265.548 us; speedup vs baseline: 1.1190x; 1.0406x over previous
//
#include <hip/hip_runtime.h>
#include <stdint.h>
#include <math.h>

// Problem constants (fixed by the reference)
constexpr int CB = 2;      // batch
constexpr int CS = 2048;   // seq (cutoff)
constexpr int CD = 1024;   // dmodel
constexpr int CE = 16;     // experts
constexpr int CK = 256;    // topk

typedef short bf16x8 __attribute__((ext_vector_type(8)));
typedef float f32x4 __attribute__((ext_vector_type(4)));

typedef __attribute__((address_space(3))) unsigned short lds_us;

// ds_read_b128 hidden from the waitcnt legalizer; ordering vs MFMA is enforced
// by the "+v" register ties on the explicit lgkmcnt asm (ties = data dep).
__device__ __forceinline__ bf16x8 ds_read128(const lds_us* p) {
    bf16x8 v;
    asm volatile("ds_read_b128 %0, %1" : "=v"(v) : "v"(p));
    return v;
}

__device__ inline unsigned short f2bf(float f) {
    union { float f; uint32_t u; } v; v.f = f;
    uint32_t u = v.u;
    uint32_t r = (u + 0x7FFFu + ((u >> 16) & 1u)) >> 16;
    return (unsigned short)r;
}

// ---------------- K1a: partial logits over a 64-d slice (+ zero y) ----------
__global__ __launch_bounds__(256)
void logits_part_kernel(const float* __restrict__ x,
                        const float* __restrict__ gate,
                        float* __restrict__ part,
                        float* __restrict__ y) {
    const int tt = blockIdx.x;       // token tile (256 tokens)
    const int dt = blockIdx.y;       // d tile (64 d)
    const int tid = threadIdx.x;

    // fold the y-zeroing in here (saves a hipMemsetAsync launch node).
    {
        const int bb = dt * 16 + tt;
        float* yb = y + (size_t)bb * 16384 + tid * 4;
        const f32x4 z = {0.f, 0.f, 0.f, 0.f};
#pragma unroll
        for (int i = 0; i < 16; i++) *(f32x4*)(yb + i * 1024) = z;
    }

    __shared__ float Xs[256 * 17];

    float acc[CE];
#pragma unroll
    for (int e = 0; e < CE; e++) acc[e] = 0.0f;

    const int tokl = tid >> 2;           // staging row within 64-token group
    const int c4 = (tid & 3) << 2;       // staging col (0,4,8,12)

    for (int dch = 0; dch < 4; dch++) {
        const int dbase = dt * 64 + dch * 16;
        __syncthreads();
#pragma unroll
        for (int q = 0; q < 4; q++) {
            const int tok = q * 64 + tokl;
            const f32x4 v = *(const f32x4*)(x + ((size_t)(tt * 256 + tok)) * CD + dbase + c4);
            Xs[tok * 17 + c4 + 0] = v[0];
            Xs[tok * 17 + c4 + 1] = v[1];
            Xs[tok * 17 + c4 + 2] = v[2];
            Xs[tok * 17 + c4 + 3] = v[3];
        }
        __syncthreads();
#pragma unroll
        for (int d = 0; d < 16; d++) {
            const float xv = Xs[tid * 17 + d];
            const float* gr = gate + (size_t)(dbase + d) * CE;  // wave-uniform
#pragma unroll
            for (int e = 0; e < CE; e++) acc[e] = fmaf(xv, gr[e], acc[e]);
        }
    }
    float* pr = part + ((size_t)dt * (CB * CS) + tt * 256 + tid) * CE;
#pragma unroll
    for (int e = 0; e < CE; e++) pr[e] = acc[e];
}

// ---------------- K1b: deterministic reduce of the 16 d-partials -------------
__global__ __launch_bounds__(256)
void logits_reduce_kernel(const float* __restrict__ part,
                          float* __restrict__ logits) {
    const int i = blockIdx.x * 256 + threadIdx.x;   // 0 .. B*S*E-1
    float s = 0.0f;
#pragma unroll
    for (int p = 0; p < 16; p++) s += part[(size_t)p * (CB * CS * CE) + i];
    logits[i] = s;
}

// ---------------- K2: per (b,e) softmax over tokens + top-256 ----------------
__global__ void topk_kernel(const float* __restrict__ logits,
                            int* __restrict__ idx_out,
                            float* __restrict__ g_out) {
    const int be = blockIdx.x;            // b*E + e
    const int b = be >> 4, e = be & 15;
    const int tid = threadIdx.x;          // 256
    const int lane = tid & 63, wid = tid >> 6;

    __shared__ float redf[4];
    __shared__ int hist[256];
    __shared__ int wsum[4];
    __shared__ int sh_bin, sh_rank;
    __shared__ int scnt, eqc;
    __shared__ int eqbuf[CS];

    float lv[8], p[8];
    unsigned int uv[8];
#pragma unroll
    for (int j = 0; j < 8; j++) {
        const int s = tid + j * 256;
        lv[j] = logits[((size_t)(b * CS + s)) * CE + e];
    }
    float m = lv[0];
#pragma unroll
    for (int j = 1; j < 8; j++) m = fmaxf(m, lv[j]);
#pragma unroll
    for (int o = 32; o > 0; o >>= 1) m = fmaxf(m, __shfl_down(m, o));
    if (lane == 0) redf[wid] = m;
    __syncthreads();
    m = fmaxf(fmaxf(redf[0], redf[1]), fmaxf(redf[2], redf[3]));
    __syncthreads();
    float lsum = 0.0f;
#pragma unroll
    for (int j = 0; j < 8; j++) {
        p[j] = expf(lv[j] - m);
        uv[j] = __float_as_uint(p[j]);
        lsum += p[j];
    }
#pragma unroll
    for (int o = 32; o > 0; o >>= 1) lsum += __shfl_down(lsum, o);
    if (lane == 0) redf[wid] = lsum;
    __syncthreads();
    const float total = redf[0] + redf[1] + redf[2] + redf[3];
    const float inv_total = 1.0f / total;

    // ---- radix-256 select: find v = CK-th largest bit pattern ----
    unsigned int prefix = 0;
    int kneed = CK;
    for (int pass = 0; pass < 4; pass++) {
        const int shift = 24 - 8 * pass;
        __syncthreads();
        hist[tid] = 0;
        __syncthreads();
        const unsigned int hmask = (pass == 0) ? 0u : (0xFFFFFFFFu << (shift + 8));
#pragma unroll
        for (int j = 0; j < 8; j++)
            if ((uv[j] & hmask) == prefix)
                atomicAdd(&hist[(uv[j] >> shift) & 255], 1);
        __syncthreads();
        const int own = hist[tid];
        int s = own;
#pragma unroll
        for (int o = 1; o < 64; o <<= 1) {
            int t = __shfl_down(s, o);
            if (lane + o < 64) s += t;
        }
        if (lane == 0) wsum[wid] = s;
        __syncthreads();
        int above = 0;
        for (int ww = wid + 1; ww < 4; ww++) above += wsum[ww];
        const int incl = s + above;
        if (incl >= kneed && (incl - own) < kneed) {
            sh_bin = tid;
            sh_rank = kneed - (incl - own);
        }
        __syncthreads();
        prefix |= ((unsigned int)sh_bin) << shift;
        kneed = sh_rank;
    }
    const unsigned int v = prefix;
    const int quota = kneed;

    if (tid == 0) { scnt = 0; eqc = 0; }
    __syncthreads();
#pragma unroll
    for (int j = 0; j < 8; j++) {
        const int s = tid + j * 256;
        if (uv[j] > v) {
            const int pos = atomicAdd(&scnt, 1);
            idx_out[be * CK + pos] = s;
            g_out[be * CK + pos] = p[j] * inv_total;
        } else if (uv[j] == v) {
            const int pos = atomicAdd(&eqc, 1);
            eqbuf[pos] = s;
        }
    }
    __syncthreads();
    if (tid == 0) {
        const int cgt = scnt;
        const int n = eqc;
        const float gv = __uint_as_float(v) * inv_total;
        if (n > quota) {
            for (int i = 0; i < quota; i++) {
                int mn = i;
                for (int k2 = i + 1; k2 < n; k2++)
                    if (eqbuf[k2] < eqbuf[mn]) mn = k2;
                const int t2 = eqbuf[i]; eqbuf[i] = eqbuf[mn]; eqbuf[mn] = t2;
            }
        }
        for (int i = 0; i < quota; i++) {
            idx_out[be * CK + cgt + i] = eqbuf[i];
            g_out[be * CK + cgt + i] = gv;
        }
    }
}

// ---------------- K3: gather selected tokens, convert to bf16 ----------------
__global__ void gather_kernel(const float* __restrict__ x,
                              const int* __restrict__ idx_ws,
                              unsigned short* __restrict__ xinbuf) {
    const int row = blockIdx.x;            // be*CK + slot
    const int be = row >> 8;
    const int b = be >> 4;
    const int tok = idx_ws[row];
    const int c0 = threadIdx.x * 4;
    const f32x4 f = *(const f32x4*)(x + ((size_t)b * CS + tok) * CD + c0);
    union { unsigned short u[4]; uint2 v; } t;
    t.u[0] = f2bf(f[0]); t.u[1] = f2bf(f[1]); t.u[2] = f2bf(f[2]); t.u[3] = f2bf(f[3]);
    *(uint2*)(xinbuf + (size_t)row * CD + c0) = t.v;
}

// ---------------- K5/K6: batched GEMM per (b,e) -- DIRECT-W (no Wt) ----------
// CHANGED THIS ROUND: B operand staged directly from fp32 W[e][k][n] with an
// in-register 4x4 transpose + RNE cvt, writing the *byte-identical* Bs layout
// (slot = k-chunk ^ (n&7)) the fragment reads already use. This deletes the
// Wt intermediate entirely (wt_kernel + prep-wt: 268 MB of pipeline traffic
// -> 134 MB). A-path, K-loop, decode, and R8's LDS-transpose epilogue are
// unchanged. Per-thread B stage: 4x f32x4 loads (rows k..k+3, 512B-coalesced
// across lanes), 16 cvt, 4x ds_write_b64 (8-way conflict ~= 2.9x, benign).
#define MFMA16(A_, B_, C_) __builtin_amdgcn_mfma_f32_16x16x32_bf16((A_), (B_), (C_), 0, 0, 0)

template <int PHASE>
__global__ __launch_bounds__(512, 1)
void ffn_gemm(const unsigned short* __restrict__ Ain,
              const float* __restrict__ Wf,
              const float* __restrict__ bias,
              unsigned short* __restrict__ hout,
              const int* __restrict__ idx_ws,
              const float* __restrict__ g_ws,
              float* __restrict__ y) {
    const int id = blockIdx.x;            // 0..255
    const int xcd = id & 7;
    const int q = id >> 3;                // 0..31
    const int e = ((q & 1) << 3) | xcd;
    const int b = (q >> 1) & 1;
    const int ntile = q >> 2;             // 0..7
    const int be = b * CE + e;
    const int tid = threadIdx.x;
    const int w = tid >> 6, l = tid & 63;
    const int wm = w >> 1, wn = w & 1;    // wave grid 4(M) x 2(N)
    const int quad = l >> 4, lr = l & 15;

    // 96KB carved: Ar(32K) Aw(32K) Br(16K) Bw(16K); epilogue reuses as
    // 128x133 f32 transpose tile (68KB).
    __shared__ __align__(16) unsigned char SMEM[98304];
    unsigned short* Ar = (unsigned short*)SMEM;            // 16384 ushorts
    unsigned short* Aw = Ar + 16384;
    unsigned short* Br = Aw + 16384;                       // 8192 ushorts
    unsigned short* Bw = Br + 8192;

    f32x4 acc[4][4];
    const f32x4 zz = {0.f, 0.f, 0.f, 0.f};
#pragma unroll
    for (int mi = 0; mi < 4; mi++)
#pragma unroll
        for (int ni = 0; ni < 4; ni++) acc[mi][ni] = zz;

    const unsigned short* Agb = Ain + (size_t)be * CK * CD;        // [256][1024] bf16

    // A staging: unit u = one 16B chunk. LDS lane-linear; global chunk XOR'd.
    const unsigned short* pAg[4]; int dA[4];
#pragma unroll
    for (int j = 0; j < 4; j++) {
        const int u = w * 256 + j * 64 + l;      // 0..2047
        const int row = u >> 3;
        const int c = (u & 7) ^ (row & 7);
        pAg[j] = Agb + (size_t)row * CD + c * 8;
        dA[j] = u * 8;
    }

    // B staging from fp32 W[e][k][n]: thread owns 4k x 4n micro-tile.
    // kq = tid>>5 (0..15): rows k = kq*4..kq*4+3; nq = tid&31: cols nq*4..+3.
    const int kq = tid >> 5;
    const int nq = tid & 31;
    const float* pWg = Wf + (size_t)e * CD * CD + (size_t)(kq * 4) * CD
                          + ntile * 128 + nq * 4;
    // ds write addrs (ushort units): n*64 + ((k>>3)^(n&7))*8 + (k&7); k=kq*4
    int wbB[4];
#pragma unroll
    for (int i = 0; i < 4; i++) {
        const int n = nq * 4 + i;
        wbB[i] = n * 64 + (((kq >> 1) ^ (n & 7)) << 3) + (kq & 1) * 4;
    }

    // fragment read offsets (ushort units): row*64 + ((kk*4+quad)^(row&7))*8
    const int sc0 = (quad ^ (lr & 7)) * 8;
    const int sc1 = sc0 ^ 32;
    int offA[2][4], offB[2][4];
#pragma unroll
    for (int mi = 0; mi < 4; mi++) {
        const int r = wm * 64 + mi * 16 + lr;
        offA[0][mi] = r * 64 + sc0;
        offA[1][mi] = r * 64 + sc1;
    }
#pragma unroll
    for (int ni = 0; ni < 4; ni++) {
        const int r = wn * 64 + ni * 16 + lr;
        offB[0][ni] = r * 64 + sc0;
        offB[1][ni] = r * 64 + sc1;
    }

    // preload tile 0
    bf16x8 sA0, sA1, sA2, sA3;
    f32x4 sW0, sW1, sW2, sW3;
    sA0 = *(const bf16x8*)(pAg[0]); sA1 = *(const bf16x8*)(pAg[1]);
    sA2 = *(const bf16x8*)(pAg[2]); sA3 = *(const bf16x8*)(pAg[3]);
    sW0 = *(const f32x4*)(pWg);
    sW1 = *(const f32x4*)(pWg + CD);
    sW2 = *(const f32x4*)(pWg + 2 * CD);
    sW3 = *(const f32x4*)(pWg + 3 * CD);
    *(bf16x8*)(Ar + dA[0]) = sA0; *(bf16x8*)(Ar + dA[1]) = sA1;
    *(bf16x8*)(Ar + dA[2]) = sA2; *(bf16x8*)(Ar + dA[3]) = sA3;
#pragma unroll
    for (int i = 0; i < 4; i++) {
        union { unsigned short us[4]; uint2 v; } pk;
        pk.us[0] = f2bf(sW0[i]); pk.us[1] = f2bf(sW1[i]);
        pk.us[2] = f2bf(sW2[i]); pk.us[3] = f2bf(sW3[i]);
        *(uint2*)(Br + wbB[i]) = pk.v;
    }
    __syncthreads();

#pragma unroll 1
    for (int t = 0; t < 16; t++) {
        // issue next-tile loads early; waits land before the cvt/ds_write use
        if (t < 15) {
            const int kel = (t + 1) * 64;
            sA0 = *(const bf16x8*)(pAg[0] + kel);
            sA1 = *(const bf16x8*)(pAg[1] + kel);
            sA2 = *(const bf16x8*)(pAg[2] + kel);
            sA3 = *(const bf16x8*)(pAg[3] + kel);
            const float* pw = pWg + (size_t)kel * CD;
            sW0 = *(const f32x4*)(pw);
            sW1 = *(const f32x4*)(pw + CD);
            sW2 = *(const f32x4*)(pw + 2 * CD);
            sW3 = *(const f32x4*)(pw + 3 * CD);
        }
        bf16x8 a0, a1, a2, a3, b0, b1, b2, b3;
#pragma unroll
        for (int kk = 0; kk < 2; kk++) {
            a0 = ds_read128((lds_us*)Ar + offA[kk][0]);
            a1 = ds_read128((lds_us*)Ar + offA[kk][1]);
            a2 = ds_read128((lds_us*)Ar + offA[kk][2]);
            a3 = ds_read128((lds_us*)Ar + offA[kk][3]);
            b0 = ds_read128((lds_us*)Br + offB[kk][0]);
            b1 = ds_read128((lds_us*)Br + offB[kk][1]);
            b2 = ds_read128((lds_us*)Br + offB[kk][2]);
            b3 = ds_read128((lds_us*)Br + offB[kk][3]);
            asm volatile("s_waitcnt lgkmcnt(0)"
                         : "+v"(a0), "+v"(a1), "+v"(a2), "+v"(a3),
                           "+v"(b0), "+v"(b1), "+v"(b2), "+v"(b3) :: "memory");
            __builtin_amdgcn_s_setprio(1);
            acc[0][0] = MFMA16(a0, b0, acc[0][0]);
            acc[1][0] = MFMA16(a1, b0, acc[1][0]);
            acc[2][0] = MFMA16(a2, b0, acc[2][0]);
            acc[3][0] = MFMA16(a3, b0, acc[3][0]);
            acc[0][1] = MFMA16(a0, b1, acc[0][1]);
            acc[1][1] = MFMA16(a1, b1, acc[1][1]);
            acc[2][1] = MFMA16(a2, b1, acc[2][1]);
            acc[3][1] = MFMA16(a3, b1, acc[3][1]);
            acc[0][2] = MFMA16(a0, b2, acc[0][2]);
            acc[1][2] = MFMA16(a1, b2, acc[1][2]);
            acc[2][2] = MFMA16(a2, b2, acc[2][2]);
            acc[3][2] = MFMA16(a3, b2, acc[3][2]);
            acc[0][3] = MFMA16(a0, b3, acc[0][3]);
            acc[1][3] = MFMA16(a1, b3, acc[1][3]);
            acc[2][3] = MFMA16(a2, b3, acc[2][3]);
            acc[3][3] = MFMA16(a3, b3, acc[3][3]);
            __builtin_amdgcn_s_setprio(0);
        }
        if (t < 15) {
            *(bf16x8*)(Aw + dA[0]) = sA0; *(bf16x8*)(Aw + dA[1]) = sA1;
            *(bf16x8*)(Aw + dA[2]) = sA2; *(bf16x8*)(Aw + dA[3]) = sA3;
#pragma unroll
            for (int i = 0; i < 4; i++) {
                union { unsigned short us[4]; uint2 v; } pk;
                pk.us[0] = f2bf(sW0[i]); pk.us[1] = f2bf(sW1[i]);
                pk.us[2] = f2bf(sW2[i]); pk.us[3] = f2bf(sW3[i]);
                *(uint2*)(Bw + wbB[i]) = pk.v;
            }
            __syncthreads();
            unsigned short* tp = Ar; Ar = Aw; Aw = tp;
            tp = Br; Br = Bw; Bw = tp;
        }
    }

    // ---- epilogue: LDS transpose -> full-line writes (unchanged from R8) ----
    __syncthreads();                       // staging buffers dead from here
    float* LT = (float*)SMEM;              // 128 x 133 f32 = 68 KB
#pragma unroll 1
    for (int h = 0; h < 2; h++) {
        if ((wm >> 1) == h) {
            const int rb = (wm & 1) * 64;
#pragma unroll
            for (int mi = 0; mi < 4; mi++)
#pragma unroll
                for (int ni = 0; ni < 4; ni++)
#pragma unroll
                    for (int r = 0; r < 4; r++)
                        LT[(rb + mi * 16 + quad * 4 + r) * 133 + wn * 64 + ni * 16 + lr] =
                            acc[mi][ni][r];
        }
        __syncthreads();
        if (PHASE == 0) {
#pragma unroll
            for (int rr = 0; rr < 4; rr++) {
                const int row = w * 16 + rr * 4 + (l >> 4);
                const int col = (l & 15) * 8;
                const int slot = h * 128 + row;
                const float* lrow = LT + row * 133 + col;
                const float* brow = bias + e * CD + ntile * 128 + col;
                union { unsigned short us[8]; uint4 v; } pk;
#pragma unroll
                for (int i = 0; i < 8; i++)
                    pk.us[i] = f2bf(fmaxf(lrow[i] + brow[i], 0.0f));
                *(uint4*)(hout + ((size_t)be * CK + slot) * CD + ntile * 128 + col) = pk.v;
            }
        } else {
#pragma unroll 1
            for (int rr = 0; rr < 16; rr++) {
                const int row = w * 16 + rr;
                const int slot = h * 128 + row;
                const int tok = idx_ws[be * CK + slot];
                const float gval = g_ws[be * CK + slot];
                float* yrow = y + ((size_t)b * CS + tok) * CD + ntile * 128;
                const float* lrow = LT + row * 133;
                const float* brow = bias + ntile * 128;
#pragma unroll
                for (int i = 0; i < 2; i++) {
                    const int col = i * 64 + l;
                    atomicAdd(&yrow[col], (lrow[col] + brow[col]) * gval);
                }
            }
        }
        __syncthreads();
    }
}

extern "C" void kernel_launch(void* const* d_in, const int* in_sizes, int n_in,
                              void* d_out, int out_size, void* d_ws, size_t ws_size,
                              hipStream_t stream) {
    const float* x    = (const float*)d_in[0];
    const float* gate = (const float*)d_in[1];
    const float* W1   = (const float*)d_in[2];
    const float* b1   = (const float*)d_in[3];
    const float* W2   = (const float*)d_in[4];
    const float* b2   = (const float*)d_in[5];
    float* y = (float*)d_out;

    // workspace layout (bytes):
    //   logits: 0         .. 262144     (B*S*E fp32)
    //   idx:    262144    .. +32768
    //   g:      294912    .. +32768
    //   xin:    327680    .. +16.78MB   (bf16)
    //   hbuf:   17104896  .. +16.78MB   (bf16)  [aliased: logits partials 4MB]
    char* ws = (char*)d_ws;
    float* logits = (float*)ws;
    int* idxw = (int*)(ws + 262144);
    float* gw = (float*)(ws + 294912);
    unsigned short* xinbuf = (unsigned short*)(ws + 327680);
    unsigned short* hbuf = (unsigned short*)(ws + 17104896);
    float* partbuf = (float*)(ws + 17104896);   // lifetime disjoint from hbuf

    // 6 launches: Wt intermediate eliminated (GEMMs consume W1/W2 fp32 direct).
    logits_part_kernel<<<dim3(16, 16), 256, 0, stream>>>(x, gate, partbuf, y);
    logits_reduce_kernel<<<CB * CS * CE / 256, 256, 0, stream>>>(partbuf, logits);
    topk_kernel<<<CB * CE, 256, 0, stream>>>(logits, idxw, gw);
    gather_kernel<<<CB * CE * CK, 256, 0, stream>>>(x, idxw, xinbuf);
    ffn_gemm<0><<<256, 512, 0, stream>>>(xinbuf, W1, b1, hbuf, idxw, gw, y);
    ffn_gemm<1><<<256, 512, 0, stream>>>(hbuf, W2, b2, nullptr, idxw, gw, y);
}